// Round 6
// baseline (1050.362 us; speedup 1.0000x reference)
//
#include <hip/hip_runtime.h>

typedef unsigned short u16;
typedef __attribute__((ext_vector_type(8))) short short8;
typedef __attribute__((ext_vector_type(4))) float f32x4;

#define DE 512   // embed / model dim
#define SL 2048  // sequence length
#define NB 4     // batch
#define NH 8     // heads
#define HD 64    // head dim

__device__ __forceinline__ float bf2f(u16 h) {
    union { unsigned u; float f; } v; v.u = ((unsigned)h) << 16; return v.f;
}
__device__ __forceinline__ u16 f2bf(float f) {
    union { float f; unsigned u; } v; v.f = f;
    unsigned u = v.u;
    return (u16)((u + 0x7FFFu + ((u >> 16) & 1u)) >> 16);  // RNE
}
// load 8 consecutive fp32, round to bf16 fragment
__device__ __forceinline__ short8 ld8f(const float* __restrict__ p) {
    const float4 a = *(const float4*)p;
    const float4 b = *(const float4*)(p + 4);
    short8 r;
    ((u16*)&r)[0] = f2bf(a.x); ((u16*)&r)[1] = f2bf(a.y);
    ((u16*)&r)[2] = f2bf(a.z); ((u16*)&r)[3] = f2bf(a.w);
    ((u16*)&r)[4] = f2bf(b.x); ((u16*)&r)[5] = f2bf(b.y);
    ((u16*)&r)[6] = f2bf(b.z); ((u16*)&r)[7] = f2bf(b.w);
    return r;
}

// fp32 -> bf16 conversion pass; blockIdx.y selects one of 3 source arrays.
__global__ __launch_bounds__(256) void cvt3(const float* __restrict__ s0,
                                            const float* __restrict__ s1,
                                            const float* __restrict__ s2,
                                            u16* __restrict__ dst, int per) {
    const float* src = (blockIdx.y == 0) ? s0 : ((blockIdx.y == 1) ? s1 : s2);
    const int idx = (blockIdx.x * 256 + threadIdx.x) * 8;
    if (idx >= per) return;
    short8 v = ld8f(src + idx);
    *(short8*)(dst + (size_t)blockIdx.y * per + idx) = v;
}

// async 16B global -> LDS
__device__ __forceinline__ void llds16(const u16* g, u16* l) {
    __builtin_amdgcn_global_load_lds((const __attribute__((address_space(1))) void*)g,
                                     (__attribute__((address_space(3))) void*)l, 16, 0, 0);
}

// ---------------- 64x64-tile LDS-staged GEMM body (bf16 MFMA) ----------------
// C[t][c] = sum_k X[t][k]*W[c][k] + bias[c], K = 512, bf16 inputs.
// 256 threads = 4 waves; wave w owns 32x32 (wr=w>>1, wc=w&1); BK=64, dbuf LDS.
// XOR swizzle, both sides (rule 21): linear LDS dest (tid*16B), pre-swizzled
// global source chunk ( (tid&7) ^ (row&7) ), swizzled ds_read. Conflict-free.
// mode 0: fp32 out [t][512]; mode 1: bf16 head-split [b][h][t][64];
// mode 2: bf16 head-split transposed+k-permuted [b][h][d][t'] where within each
//         32-token group, t' = quad*8 + m*4 + r for t = m*16 + quad*4 + r.
//         (matches the swapped-QK in-register PV fragment order in attn_kernel)
__device__ __forceinline__ void gemm64_body(u16* As, u16* Bs,   // each [2][4096] u16
                                            const u16* __restrict__ X,
                                            const u16* __restrict__ W,
                                            const float* __restrict__ bias,
                                            void* __restrict__ outv,
                                            int mode, int tok0, int col0) {
    const int tid = threadIdx.x;
    const int l = tid & 63, w = tid >> 6;
    const int q16 = l & 15, quad = l >> 4;
    const int wr = w >> 1, wc = w & 1;

    const int srow = tid >> 3;                          // 0..31
    const int scol = ((tid & 7) ^ (srow & 7)) * 8;      // u16 units, pre-swizzled
    const u16* ga = X + (size_t)(tok0 + srow) * DE + scol;
    const u16* gb = W + (size_t)(col0 + srow) * DE + scol;
    u16* la = As + tid * 8;
    u16* lb = Bs + tid * 8;

    f32x4 acc[2][2] = {};

    #pragma unroll
    for (int i = 0; i < 2; ++i) {
        llds16(ga + (size_t)i * 32 * DE, la + i * 2048);
        llds16(gb + (size_t)i * 32 * DE, lb + i * 2048);
    }
    __syncthreads();

    int cur = 0;
    for (int ks = 64; ks <= DE; ks += 64) {
        if (ks < DE) {
            u16* da = la + (cur ^ 1) * 4096;
            u16* db = lb + (cur ^ 1) * 4096;
            #pragma unroll
            for (int i = 0; i < 2; ++i) {
                llds16(ga + (size_t)i * 32 * DE + ks, da + i * 2048);
                llds16(gb + (size_t)i * 32 * DE + ks, db + i * 2048);
            }
        }
        const char* Ab = (const char*)(As + cur * 4096);
        const char* Bb = (const char*)(Bs + cur * 4096);
        #pragma unroll
        for (int kk = 0; kk < 64; kk += 32) {
            short8 af[2], bf[2];
            #pragma unroll
            for (int m = 0; m < 2; ++m) {
                const int row = wr * 32 + m * 16 + q16;
                af[m] = *(const short8*)(Ab + row * 128 + (((kk + quad * 8) * 2) ^ ((q16 & 7) << 4)));
            }
            #pragma unroll
            for (int n = 0; n < 2; ++n) {
                const int row = wc * 32 + n * 16 + q16;
                bf[n] = *(const short8*)(Bb + row * 128 + (((kk + quad * 8) * 2) ^ ((q16 & 7) << 4)));
            }
            #pragma unroll
            for (int m = 0; m < 2; ++m)
                #pragma unroll
                for (int n = 0; n < 2; ++n)
                    acc[m][n] = __builtin_amdgcn_mfma_f32_16x16x32_bf16(af[m], bf[n], acc[m][n], 0, 0, 0);
        }
        __syncthreads();
        cur ^= 1;
    }

    #pragma unroll
    for (int n = 0; n < 2; ++n) {
        const int col = col0 + wc * 32 + n * 16 + q16;   // C/D col = lane&15
        const float bv = bias[col];
        #pragma unroll
        for (int m = 0; m < 2; ++m) {
            const f32x4 a4 = acc[m][n];
            const int tg0 = tok0 + wr * 32 + m * 16 + quad * 4;  // C/D row = quad*4+r
            if (mode == 2) {
                const int b = tg0 >> 11, t0 = tg0 & 2047;
                // within-32 k-permute: t5 = m16*16 + qd*4 (+r)  ->  p5 = qd*8 + m16*4 (+r)
                const int t0p = (t0 & ~31) | ((t0 & 12) << 1) | ((t0 & 16) >> 2);
                const int h = col >> 6, d = col & 63;
                ushort4 pk;
                pk.x = f2bf(a4[0] + bv); pk.y = f2bf(a4[1] + bv);
                pk.z = f2bf(a4[2] + bv); pk.w = f2bf(a4[3] + bv);
                *(ushort4*)((u16*)outv + ((size_t)((b * NH + h) * HD + d) << 11) + t0p) = pk;
            } else if (mode == 1) {
                const int h = col >> 6, d = col & 63;
                #pragma unroll
                for (int r = 0; r < 4; ++r) {
                    const int tg = tg0 + r;
                    const int b = tg >> 11, t = tg & 2047;
                    ((u16*)outv)[(((size_t)(b * NH + h) * SL + t) << 6) + d] = f2bf(a4[r] + bv);
                }
            } else {
                #pragma unroll
                for (int r = 0; r < 4; ++r)
                    ((float*)outv)[(size_t)(tg0 + r) * DE + col] = a4[r] + bv;
            }
        }
    }
}

// Fused Q/K/V projection: blockIdx.z selects which gemm.
__global__ __launch_bounds__(256) void gemm_qkv(const u16* __restrict__ xbf,
                                                const u16* __restrict__ wbf,
                                                const float* __restrict__ bq,
                                                const float* __restrict__ bk,
                                                const float* __restrict__ bv,
                                                u16* __restrict__ outbase) {
    __shared__ __align__(16) u16 As[2][4096];
    __shared__ __align__(16) u16 Bs[2][4096];
    const int z = blockIdx.z;
    const u16* X = xbf + (size_t)z * 4194304;
    const u16* W = wbf + (size_t)z * 262144;
    const float* bias = (z == 0) ? bq : ((z == 1) ? bk : bv);
    u16* out = outbase + (size_t)z * 4194304;
    gemm64_body(&As[0][0], &Bs[0][0], X, W, bias, out,
                (z == 2) ? 2 : 1, blockIdx.x * 64, blockIdx.y * 64);
}

// Final projection: bf16 O-concat @ Wo^T + bo -> fp32 out.
__global__ __launch_bounds__(256) void gemm_fin(const u16* __restrict__ X,
                                                const u16* __restrict__ W,
                                                const float* __restrict__ bias,
                                                float* __restrict__ outp) {
    __shared__ __align__(16) u16 As[2][4096];
    __shared__ __align__(16) u16 Bs[2][4096];
    gemm64_body(&As[0][0], &Bs[0][0], X, W, bias, outp,
                0, blockIdx.x * 64, blockIdx.y * 64);
}

// Two-pass, P-in-registers attention. Block = (b,h,16 q-rows), 8 waves, wave
// owns a 256-wide k-strip. Swapped QK^T (mfma(K,Q)): lane (q16,quad) holds
// S[q=q16][k=kb+quad*4+r].
// Pass 1: rowsums only (no stores). Pass 2: recompute u (QK^T is cheap), write
// normalized attn DIRECTLY from registers (f32 nontemporal), and run PV with
// the lane-local u as the A-frag (k-order quad*8+t*4+r; Vt stored pre-permuted
// to match -> zero shuffles, 16B V loads). PV is 8-way split-K; partials
// combined via padded LDS. No P buffer: LDS ~34 KB -> 3 blocks/CU.
__global__ __launch_bounds__(512) void attn_kernel(const u16* __restrict__ Q,
                                                   const u16* __restrict__ K,
                                                   const u16* __restrict__ Vt,
                                                   const int* __restrict__ mask,
                                                   float* __restrict__ attn_out,
                                                   u16* __restrict__ Obuf) {
    __shared__ float partial[16][8];
    __shared__ float linv[16];
    __shared__ float Ored[8][16][65];   // +1 pad: conflict-free partial writes

    const int tid = threadIdx.x;
    const int lane = tid & 63, wave = tid >> 6;  // 8 waves
    const int q16 = lane & 15, quad = lane >> 4;
    const int qblk = blockIdx.x, h = blockIdx.y, b = blockIdx.z;
    const int qbase = qblk * 16;

    const u16* qplane = Q + (size_t)((b * NH + h) * SL) * HD;
    const u16* kplane = K + (size_t)((b * NH + h) * SL) * HD;
    const u16* vplane = Vt + (size_t)((b * NH + h) * HD) * SL;

    // Q frags (B-operand of swapped MFMA): lane q16 -> q-row qbase+q16
    const u16* qrow = qplane + (qbase + q16) * HD + quad * 8;
    const short8 aq0 = *(const short8*)(qrow);
    const short8 aq1 = *(const short8*)(qrow + 32);

    const int k0 = wave * 256;
    const int* mrowp = mask + (size_t)(b * SL + qbase + q16) * SL;  // lane's q-row

    // ---- Pass 1: rowsums over this wave's k-strip ----
    float rs = 0.f;
    #pragma unroll 4
    for (int kt = 0; kt < 16; ++kt) {
        const int kb = k0 + kt * 16;
        const u16* krow = kplane + (kb + q16) * HD + quad * 8;
        const short8 b0 = *(const short8*)(krow);
        const short8 b1 = *(const short8*)(krow + 32);
        const int4 m4 = *(const int4*)(mrowp + kb + quad * 4);
        f32x4 s = {};
        s = __builtin_amdgcn_mfma_f32_16x16x32_bf16(b0, aq0, s, 0, 0, 0);
        s = __builtin_amdgcn_mfma_f32_16x16x32_bf16(b1, aq1, s, 0, 0, 0);
        const float u0 = m4.x ? 0.0f : __expf(s[0] * 0.125f);
        const float u1 = m4.y ? 0.0f : __expf(s[1] * 0.125f);
        const float u2 = m4.z ? 0.0f : __expf(s[2] * 0.125f);
        const float u3 = m4.w ? 0.0f : __expf(s[3] * 0.125f);
        rs += (u0 + u1) + (u2 + u3);
    }
    rs += __shfl_xor(rs, 16);
    rs += __shfl_xor(rs, 32);
    if (lane < 16) partial[lane][wave] = rs;
    __syncthreads();
    if (tid < 16) {
        float s = 0.f;
        #pragma unroll
        for (int w = 0; w < 8; ++w) s += partial[tid][w];
        linv[tid] = 1.0f / s;
    }
    __syncthreads();
    const float inv = linv[q16];

    // ---- Pass 2: recompute u; write normalized attn from regs; PV in-reg ----
    f32x4 o0 = {}, o1 = {}, o2 = {}, o3 = {};
    const size_t arowbase = ((size_t)((b * NH + h) * SL + qbase + q16)) * SL;
    #pragma unroll 2
    for (int c = 0; c < 8; ++c) {
        const int kb = k0 + c * 32;
        // tile 0: k = kb .. kb+15
        const u16* kr0 = kplane + (kb + q16) * HD + quad * 8;
        const short8 b0 = *(const short8*)(kr0);
        const short8 b1 = *(const short8*)(kr0 + 32);
        const int4 m4a = *(const int4*)(mrowp + kb + quad * 4);
        f32x4 s = {};
        s = __builtin_amdgcn_mfma_f32_16x16x32_bf16(b0, aq0, s, 0, 0, 0);
        s = __builtin_amdgcn_mfma_f32_16x16x32_bf16(b1, aq1, s, 0, 0, 0);
        const float u0 = m4a.x ? 0.0f : __expf(s[0] * 0.125f);
        const float u1 = m4a.y ? 0.0f : __expf(s[1] * 0.125f);
        const float u2 = m4a.z ? 0.0f : __expf(s[2] * 0.125f);
        const float u3 = m4a.w ? 0.0f : __expf(s[3] * 0.125f);
        f32x4 w0; w0[0] = u0 * inv; w0[1] = u1 * inv; w0[2] = u2 * inv; w0[3] = u3 * inv;
        __builtin_nontemporal_store(w0, (f32x4*)(attn_out + arowbase + kb + quad * 4));
        uint2 pk0;
        pk0.x = (unsigned)f2bf(u0) | ((unsigned)f2bf(u1) << 16);
        pk0.y = (unsigned)f2bf(u2) | ((unsigned)f2bf(u3) << 16);

        // tile 1: k = kb+16 .. kb+31
        const u16* kr1 = kplane + (kb + 16 + q16) * HD + quad * 8;
        const short8 c0 = *(const short8*)(kr1);
        const short8 c1 = *(const short8*)(kr1 + 32);
        const int4 m4b = *(const int4*)(mrowp + kb + 16 + quad * 4);
        f32x4 t = {};
        t = __builtin_amdgcn_mfma_f32_16x16x32_bf16(c0, aq0, t, 0, 0, 0);
        t = __builtin_amdgcn_mfma_f32_16x16x32_bf16(c1, aq1, t, 0, 0, 0);
        const float v0 = m4b.x ? 0.0f : __expf(t[0] * 0.125f);
        const float v1 = m4b.y ? 0.0f : __expf(t[1] * 0.125f);
        const float v2 = m4b.z ? 0.0f : __expf(t[2] * 0.125f);
        const float v3 = m4b.w ? 0.0f : __expf(t[3] * 0.125f);
        f32x4 w1; w1[0] = v0 * inv; w1[1] = v1 * inv; w1[2] = v2 * inv; w1[3] = v3 * inv;
        __builtin_nontemporal_store(w1, (f32x4*)(attn_out + arowbase + kb + 16 + quad * 4));
        uint2 pk1;
        pk1.x = (unsigned)f2bf(v0) | ((unsigned)f2bf(v1) << 16);
        pk1.y = (unsigned)f2bf(v2) | ((unsigned)f2bf(v3) << 16);

        // PV: a-frag = lane's own u values in k' = quad*8 + t*4 + r order;
        // Vt is stored with matching column permutation -> plain 16B loads.
        union { uint4 u; short8 s8; } af;
        af.u.x = pk0.x; af.u.y = pk0.y; af.u.z = pk1.x; af.u.w = pk1.y;
        const u16* vb = vplane + (size_t)q16 * SL + kb + quad * 8;
        const short8 bv0 = *(const short8*)(vb);
        const short8 bv1 = *(const short8*)(vb + 16 * SL);
        const short8 bv2 = *(const short8*)(vb + 32 * SL);
        const short8 bv3 = *(const short8*)(vb + 48 * SL);
        o0 = __builtin_amdgcn_mfma_f32_16x16x32_bf16(af.s8, bv0, o0, 0, 0, 0);
        o1 = __builtin_amdgcn_mfma_f32_16x16x32_bf16(af.s8, bv1, o1, 0, 0, 0);
        o2 = __builtin_amdgcn_mfma_f32_16x16x32_bf16(af.s8, bv2, o2, 0, 0, 0);
        o3 = __builtin_amdgcn_mfma_f32_16x16x32_bf16(af.s8, bv3, o3, 0, 0, 0);
    }

    // ---- combine 8-way split-K PV partials ----
    #pragma unroll
    for (int r = 0; r < 4; ++r) {
        Ored[wave][quad * 4 + r][q16]      = o0[r];
        Ored[wave][quad * 4 + r][16 + q16] = o1[r];
        Ored[wave][quad * 4 + r][32 + q16] = o2[r];
        Ored[wave][quad * 4 + r][48 + q16] = o3[r];
    }
    __syncthreads();
    {
        const int qq = tid >> 5, d0 = (tid & 31) * 2;
        float a0 = 0.f, a1 = 0.f;
        #pragma unroll
        for (int w = 0; w < 8; ++w) {
            a0 += Ored[w][qq][d0];
            a1 += Ored[w][qq][d0 + 1];
        }
        const float iv = linv[qq];
        ushort2 pk;
        pk.x = f2bf(a0 * iv);
        pk.y = f2bf(a1 * iv);
        *(ushort2*)&Obuf[(size_t)(b * SL + qbase + qq) * DE + h * HD + d0] = pk;
    }
}

extern "C" void kernel_launch(void* const* d_in, const int* in_sizes, int n_in,
                              void* d_out, int out_size, void* d_ws, size_t ws_size,
                              hipStream_t stream) {
    const float* x_q = (const float*)d_in[0];
    const float* x_k = (const float*)d_in[1];
    const float* x_v = (const float*)d_in[2];
    const int* mask = (const int*)d_in[3];
    const float* Wq = (const float*)d_in[4];
    const float* bq = (const float*)d_in[5];
    const float* Wk = (const float*)d_in[6];
    const float* bk = (const float*)d_in[7];
    const float* Wv = (const float*)d_in[8];
    const float* bv = (const float*)d_in[9];
    const float* Wo = (const float*)d_in[10];
    const float* bo = (const float*)d_in[11];

    // ws layout: q | k | vt | o_cat, each B*H*L*HD = 4,194,304 bf16 (8 MiB) -> 32 MiB
    u16* ws = (u16*)d_ws;
    u16* qb = ws;
    u16* vt = ws + 2 * 4194304;
    u16* ob = ws + 3 * 4194304;

    float* outp = (float*)d_out;
    float* attn_out = outp + 4194304;  // final is B*L*DE = 4,194,304 elems

    // Scratch for bf16 pre-converted X and W lives in the attn output region:
    // consumed by the QKV gemms (before attn_kernel), then fully overwritten
    // by attn_kernel's real output.
    u16* xbf = (u16*)attn_out;                 // 3 x 4,194,304 u16 (24 MiB)
    u16* wbf = xbf + 3 * 4194304;              // 3 x   262,144 u16 (1.5 MiB)

    cvt3<<<dim3(2048, 3), 256, 0, stream>>>(x_q, x_k, x_v, xbf, 4194304);
    cvt3<<<dim3(128, 3), 256, 0, stream>>>(Wq, Wk, Wv, wbf, 262144);

    // Fused QKV projection: 3072 blocks in one dispatch.
    gemm_qkv<<<dim3(128, 8, 3), 256, 0, stream>>>(xbf, wbf, bq, bk, bv, ws);

    attn_kernel<<<dim3(128, 8, 4), 512, 0, stream>>>(qb, ws + 4194304, vt, mask, attn_out, ob);

    // Wo -> bf16 into the now-dead Q region of ws, then final projection.
    cvt3<<<dim3(128, 1), 256, 0, stream>>>(Wo, Wo, Wo, qb, 262144);
    gemm_fin<<<dim3(128, 8), 256, 0, stream>>>(ob, qb, bo, outp);
}